// Round 15
// baseline (160.086 us; speedup 1.0000x reference)
//
#include <hip/hip_runtime.h>
#include <hip/hip_bf16.h>
#include <stdint.h>

#define N_ROWS 8192
#define M_ROWS 16384
#define CDIM 128
#define MSPLIT 32      // B slices
#define SLICE_ROWS 512
#define NT 16          // 32-row B tiles per slice

typedef unsigned short u16;
typedef __attribute__((ext_vector_type(8))) short bf16x8;
typedef __attribute__((ext_vector_type(16))) float f32x16;

static __device__ __forceinline__ u16 f2bf(float x) {
  union { float f; uint32_t u; } v; v.f = x;
  uint32_t u = v.u;
  uint32_t r = u + 0x7FFFu + ((u >> 16) & 1u);  // RTNE
  return (u16)(r >> 16);
}
static __device__ __forceinline__ float bf2f(u16 b) {
  union { uint32_t u; float f; } v; v.u = ((uint32_t)b) << 16;
  return v.f;
}

// One wave per row. fp32 -> bf16, row sum-of-squares (fp32 accum), and
// FRAGMENT-ORDER store: the 16B chunk for (tile=row>>5, ks, lane') lands at
// ((tile*8+ks)*64 + lane')*16B, lane' = l5*32 + (row&31). Makes every gemm
// fragment load a single coalesced base+lane*16 transaction (round-11
// post-mortem: row-strided fragment loads shattered into 32 segments/instr).
__global__ __launch_bounds__(256) void prep_kernel(
    const float* __restrict__ f, const float* __restrict__ m,
    u16* __restrict__ fb, u16* __restrict__ mb,
    float* __restrict__ f2, float* __restrict__ mh, int* __restrict__ mind2)
{
  const int row = blockIdx.x * 4 + (threadIdx.x >> 6);
  const int lane = threadIdx.x & 63;
  const bool isF = row < N_ROWS;
  const int r = isF ? row : row - N_ROWS;
  const float* src = (isF ? f : m) + (size_t)r * CDIM;
  float2 v = *(const float2*)(src + lane * 2);
  u16 b0 = f2bf(v.x), b1 = f2bf(v.y);
  float x0 = bf2f(b0), x1 = bf2f(b1);
  float s = x0 * x0 + x1 * x1;
#pragma unroll
  for (int mask = 1; mask < 64; mask <<= 1)
    s += __shfl_xor(s, mask, 64);

  const int t = r >> 5, lr = r & 31;
  const int ks = lane >> 3;
  const int l5p = (lane >> 2) & 1;
  const int j = (lane & 3) * 2;
  u16* dst = (isF ? fb : mb)
             + ((size_t)(t * 8 + ks) * 64 + l5p * 32 + lr) * 8 + j;
  dst[0] = b0; dst[1] = b1;
  if (lane == 0) {
    if (isF) { f2[r] = s; mind2[r] = 0x7F7FFFFF; }  // +FLT_MAX bits
    else     { mh[r] = -0.5f * s; }
  }
}

// ZERO-LDS, ZERO-BARRIER register GEMM on fragment-order inputs, now at
// 4 waves/SIMD (round-12 post-mortem: ~450 cyc/tile stall at 2 waves/SIMD;
// VGPR=112 <= 128 allows 4). Block = 4 free-running waves; wave tile
// 64A x 32B via mfma_f32_32x32x16_bf16. af: 16 coalesced 16B loads (64
// VGPR, once). B streams global->VGPR as 8 x 1KB coalesced loads per
// 32-row tile, double-buffered one tile ahead; dual accumulators overlap
// the fold-VALU of tile t with MFMA of t+1. acc seeded with mh=-m2/2
// (C/D col==l31 for all regs), so min d2 = f2 - 2*max(acc).
// grid (32 msplit, 32 abase) = 1024 blocks = 4/CU = 16 waves/CU;
// msplit%8 pins the XCD (4 x 128 KB B-slices per XCD, L2-resident).
__global__ __launch_bounds__(256, 4) void gemm_min_kernel(
    const u16* __restrict__ fb, const u16* __restrict__ mb,
    const float* __restrict__ f2, const float* __restrict__ mh,
    int* __restrict__ mind2)
{
  const int tid = threadIdx.x;
  const int lane = tid & 63;
  const int w = tid >> 6;          // 0..3 : 64-row A group
  const int l31 = lane & 31;
  const int l5 = lane >> 5;        // 0/1 : k-half
  const int abase = blockIdx.y * 256;
  const size_t mslice = (size_t)blockIdx.x * SLICE_ROWS;

  // A fragments (fragment-order, coalesced): ta = abase/32 + w*2 + mi.
  bf16x8 af[2][8];  // [mi][ks]
#pragma unroll
  for (int mi = 0; mi < 2; ++mi) {
    const int ta = (abase >> 5) + w * 2 + mi;
#pragma unroll
    for (int ks = 0; ks < 8; ++ks)
      af[mi][ks] = *(const bf16x8*)&fb[((size_t)(ta * 8 + ks) * 64 + lane) * 8];
  }

  // B fragment stream base: tile tb = mslice/32 + t.
  const u16* bbase = mb + ((size_t)(mslice >> 5) * 8 * 64) * 8;
  const float* mhp = mh + mslice + l31;

  bf16x8 bgA[8], bgB[8];
  float mhA, mhB;
#pragma unroll
  for (int ks = 0; ks < 8; ++ks)
    bgA[ks] = *(const bf16x8*)&bbase[((size_t)ks * 64 + lane) * 8];  // tile 0
  mhA = mhp[0];

  float tmax[2][16];
#pragma unroll
  for (int mi = 0; mi < 2; ++mi)
#pragma unroll
    for (int r = 0; r < 16; ++r) tmax[mi][r] = -3.0e38f;

  f32x16 accA[2], accB[2];
#pragma unroll
  for (int mi = 0; mi < 2; ++mi)
#pragma unroll
    for (int r = 0; r < 16; ++r) accB[mi][r] = -3.0e38f;  // first fold no-op

  for (int t = 0; t < NT; t += 2) {
    // Prefetch tile t+1 into bgB (coalesced 1KB loads).
    {
      const u16* bp1 = bbase + (size_t)(t + 1) * (8 * 64 * 8);
#pragma unroll
      for (int ks = 0; ks < 8; ++ks)
        bgB[ks] = *(const bf16x8*)&bp1[((size_t)ks * 64 + lane) * 8];
      mhB = mhp[(t + 1) * 32];
    }
    // Seed accA with -m2/2, compute tile t; fold tile t-1 (accB) meanwhile.
#pragma unroll
    for (int mi = 0; mi < 2; ++mi)
#pragma unroll
      for (int r = 0; r < 16; ++r) accA[mi][r] = mhA;
#pragma unroll
    for (int ks = 0; ks < 8; ++ks)
#pragma unroll
      for (int mi = 0; mi < 2; ++mi)
        accA[mi] = __builtin_amdgcn_mfma_f32_32x32x16_bf16(
            af[mi][ks], bgA[ks], accA[mi], 0, 0, 0);
#pragma unroll
    for (int mi = 0; mi < 2; ++mi)
#pragma unroll
      for (int r = 0; r < 16; ++r)
        tmax[mi][r] = fmaxf(tmax[mi][r], accB[mi][r]);

    // Prefetch tile t+2 into bgA (wraps harmlessly at the end).
    {
      const u16* bp2 = bbase + (size_t)((t + 2) & (NT - 1)) * (8 * 64 * 8);
#pragma unroll
      for (int ks = 0; ks < 8; ++ks)
        bgA[ks] = *(const bf16x8*)&bp2[((size_t)ks * 64 + lane) * 8];
      mhA = mhp[((t + 2) & (NT - 1)) * 32];
    }
    // Seed accB, compute tile t+1; fold tile t (accA) meanwhile.
#pragma unroll
    for (int mi = 0; mi < 2; ++mi)
#pragma unroll
      for (int r = 0; r < 16; ++r) accB[mi][r] = mhB;
#pragma unroll
    for (int ks = 0; ks < 8; ++ks)
#pragma unroll
      for (int mi = 0; mi < 2; ++mi)
        accB[mi] = __builtin_amdgcn_mfma_f32_32x32x16_bf16(
            af[mi][ks], bgB[ks], accB[mi], 0, 0, 0);
#pragma unroll
    for (int mi = 0; mi < 2; ++mi)
#pragma unroll
      for (int r = 0; r < 16; ++r)
        tmax[mi][r] = fmaxf(tmax[mi][r], accA[mi][r]);
  }
  // Fold the last odd tile (accB of t=NT-1).
#pragma unroll
  for (int mi = 0; mi < 2; ++mi)
#pragma unroll
    for (int r = 0; r < 16; ++r)
      tmax[mi][r] = fmaxf(tmax[mi][r], accB[mi][r]);

  // Reduce across the 32 lanes (l31) holding a row's B-columns.
#pragma unroll
  for (int mi = 0; mi < 2; ++mi)
#pragma unroll
    for (int r = 0; r < 16; ++r) {
      float tv = tmax[mi][r];
      tv = fmaxf(tv, __shfl_xor(tv, 1, 64));
      tv = fmaxf(tv, __shfl_xor(tv, 2, 64));
      tv = fmaxf(tv, __shfl_xor(tv, 4, 64));
      tv = fmaxf(tv, __shfl_xor(tv, 8, 64));
      tv = fmaxf(tv, __shfl_xor(tv, 16, 64));
      tmax[mi][r] = tv;
    }
  if (l31 == 0) {  // lanes 0 and 32 (l5 = 0/1)
#pragma unroll
    for (int mi = 0; mi < 2; ++mi)
#pragma unroll
      for (int r = 0; r < 16; ++r) {
        // C/D: row = (r&3) + 8*(r>>2) + 4*l5 within the 32-row fragment.
        const int row = abase + w * 64 + mi * 32
                        + (r & 3) + 8 * (r >> 2) + 4 * l5;
        const float d2 = fmaxf(fmaf(-2.0f, tmax[mi][r], f2[row]), 0.0f);
        atomicMin(&mind2[row], __float_as_int(d2));
      }
  }
}

__global__ __launch_bounds__(256) void finalize_kernel(
    const int* __restrict__ mind2, float* __restrict__ out)
{
  const int i = blockIdx.x * 256 + threadIdx.x;
  out[i] = sqrtf(fmaxf(__int_as_float(mind2[i]), 0.0f));
}

extern "C" void kernel_launch(void* const* d_in, const int* in_sizes, int n_in,
                              void* d_out, int out_size, void* d_ws, size_t ws_size,
                              hipStream_t stream) {
  const float* f = (const float*)d_in[0];  // features  [8192,1,1,128] fp32
  const float* m = (const float*)d_in[1];  // patch_mem [1,16384,1,128] fp32

  char* ws = (char*)d_ws;
  u16*  fb    = (u16*)(ws);                                   // 2 MB (fragment order)
  u16*  mb    = (u16*)(ws + (2u << 20));                      // 4 MB (fragment order)
  float* f2   = (float*)(ws + (2u << 20) + (4u << 20));       // 32 KB
  float* mh   = (float*)(ws + (2u << 20) + (4u << 20) + (32u << 10));  // 64 KB
  int*  mind2 = (int*)(ws + (2u << 20) + (4u << 20) + (96u << 10));    // 32 KB

  hipLaunchKernelGGL(prep_kernel, dim3((N_ROWS + M_ROWS) / 4), dim3(256), 0, stream,
                     f, m, fb, mb, f2, mh, mind2);
  hipLaunchKernelGGL(gemm_min_kernel, dim3(MSPLIT, N_ROWS / 256), dim3(256), 0, stream,
                     fb, mb, f2, mh, mind2);
  hipLaunchKernelGGL(finalize_kernel, dim3(N_ROWS / 256), dim3(256), 0, stream,
                     mind2, (float*)d_out);
}

// Round 16
// 62.478 us; speedup vs baseline: 2.5623x; 2.5623x over previous
//
#include <hip/hip_runtime.h>
#include <hip/hip_bf16.h>
#include <stdint.h>

#define N_ROWS 8192
#define M_ROWS 16384
#define CDIM 128
#define MSPLIT 32      // B slices
#define SLICE_ROWS 512
#define NT 16          // 32-row B tiles per slice

typedef unsigned short u16;
typedef __attribute__((ext_vector_type(8))) short bf16x8;
typedef __attribute__((ext_vector_type(16))) float f32x16;

static __device__ __forceinline__ u16 f2bf(float x) {
  union { float f; uint32_t u; } v; v.f = x;
  uint32_t u = v.u;
  uint32_t r = u + 0x7FFFu + ((u >> 16) & 1u);  // RTNE
  return (u16)(r >> 16);
}
static __device__ __forceinline__ float bf2f(u16 b) {
  union { uint32_t u; float f; } v; v.u = ((uint32_t)b) << 16;
  return v.f;
}

// One wave per row. fp32 -> bf16, row sum-of-squares (fp32 accum), and
// FRAGMENT-ORDER store: the 16B chunk for (tile=row>>5, ks, lane') lands at
// ((tile*8+ks)*64 + lane')*16B, lane' = l5*32 + (row&31). Makes every gemm
// fragment load a single coalesced base+lane*16 transaction (round-11
// post-mortem: row-strided fragment loads shattered into 32 segments/instr).
__global__ __launch_bounds__(256) void prep_kernel(
    const float* __restrict__ f, const float* __restrict__ m,
    u16* __restrict__ fb, u16* __restrict__ mb,
    float* __restrict__ f2, float* __restrict__ mh, int* __restrict__ mind2)
{
  const int row = blockIdx.x * 4 + (threadIdx.x >> 6);
  const int lane = threadIdx.x & 63;
  const bool isF = row < N_ROWS;
  const int r = isF ? row : row - N_ROWS;
  const float* src = (isF ? f : m) + (size_t)r * CDIM;
  float2 v = *(const float2*)(src + lane * 2);
  u16 b0 = f2bf(v.x), b1 = f2bf(v.y);
  float x0 = bf2f(b0), x1 = bf2f(b1);
  float s = x0 * x0 + x1 * x1;
#pragma unroll
  for (int mask = 1; mask < 64; mask <<= 1)
    s += __shfl_xor(s, mask, 64);

  const int t = r >> 5, lr = r & 31;
  const int ks = lane >> 3;
  const int l5p = (lane >> 2) & 1;
  const int j = (lane & 3) * 2;
  u16* dst = (isF ? fb : mb)
             + ((size_t)(t * 8 + ks) * 64 + l5p * 32 + lr) * 8 + j;
  dst[0] = b0; dst[1] = b1;
  if (lane == 0) {
    if (isF) { f2[r] = s; mind2[r] = 0x7F7FFFFF; }  // +FLT_MAX bits
    else     { mh[r] = -0.5f * s; }
  }
}

// ZERO-LDS, ZERO-BARRIER register GEMM on fragment-order inputs.
// ROUND-15 LESSON: __launch_bounds__(256,4) clamped VGPR to 64 -> 600 MB of
// scratch spills. Keep (256,2): the compiler allocates 112 VGPR, and the
// HW occupancy step (waves/CU halves at VGPR 64/128) ALREADY gives
// 4 waves/SIMD at 112 <= 128 -- no allocator constraint needed. TLP comes
// from the grid: (32 msplit, 32 abase) = 1024 blocks = 4 blocks/CU.
// Block = 4 free-running waves; wave tile 64A x 32B, mfma_f32_32x32x16_bf16.
// af: 16 coalesced 16B loads (64 VGPR, once). B streams global->VGPR as
// 8 x 1KB coalesced loads per 32-row tile, double-buffered one tile ahead;
// dual accumulators overlap the fold-VALU of tile t with MFMA of t+1.
// acc seeded with mh=-m2/2 (C/D col==l31 for all regs), so
// min d2 = f2 - 2*max(acc). msplit%8 pins the XCD (B slices L2-resident).
__global__ __launch_bounds__(256, 2) void gemm_min_kernel(
    const u16* __restrict__ fb, const u16* __restrict__ mb,
    const float* __restrict__ f2, const float* __restrict__ mh,
    int* __restrict__ mind2)
{
  const int tid = threadIdx.x;
  const int lane = tid & 63;
  const int w = tid >> 6;          // 0..3 : 64-row A group
  const int l31 = lane & 31;
  const int l5 = lane >> 5;        // 0/1 : k-half
  const int abase = blockIdx.y * 256;
  const size_t mslice = (size_t)blockIdx.x * SLICE_ROWS;

  // A fragments (fragment-order, coalesced): ta = abase/32 + w*2 + mi.
  bf16x8 af[2][8];  // [mi][ks]
#pragma unroll
  for (int mi = 0; mi < 2; ++mi) {
    const int ta = (abase >> 5) + w * 2 + mi;
#pragma unroll
    for (int ks = 0; ks < 8; ++ks)
      af[mi][ks] = *(const bf16x8*)&fb[((size_t)(ta * 8 + ks) * 64 + lane) * 8];
  }

  // B fragment stream base: tile tb = mslice/32 + t.
  const u16* bbase = mb + ((size_t)(mslice >> 5) * 8 * 64) * 8;
  const float* mhp = mh + mslice + l31;

  bf16x8 bgA[8], bgB[8];
  float mhA, mhB;
#pragma unroll
  for (int ks = 0; ks < 8; ++ks)
    bgA[ks] = *(const bf16x8*)&bbase[((size_t)ks * 64 + lane) * 8];  // tile 0
  mhA = mhp[0];

  float tmax[2][16];
#pragma unroll
  for (int mi = 0; mi < 2; ++mi)
#pragma unroll
    for (int r = 0; r < 16; ++r) tmax[mi][r] = -3.0e38f;

  f32x16 accA[2], accB[2];
#pragma unroll
  for (int mi = 0; mi < 2; ++mi)
#pragma unroll
    for (int r = 0; r < 16; ++r) accB[mi][r] = -3.0e38f;  // first fold no-op

  for (int t = 0; t < NT; t += 2) {
    // Prefetch tile t+1 into bgB (coalesced 1KB loads).
    {
      const u16* bp1 = bbase + (size_t)(t + 1) * (8 * 64 * 8);
#pragma unroll
      for (int ks = 0; ks < 8; ++ks)
        bgB[ks] = *(const bf16x8*)&bp1[((size_t)ks * 64 + lane) * 8];
      mhB = mhp[(t + 1) * 32];
    }
    // Seed accA with -m2/2, compute tile t; fold tile t-1 (accB) meanwhile.
#pragma unroll
    for (int mi = 0; mi < 2; ++mi)
#pragma unroll
      for (int r = 0; r < 16; ++r) accA[mi][r] = mhA;
#pragma unroll
    for (int ks = 0; ks < 8; ++ks)
#pragma unroll
      for (int mi = 0; mi < 2; ++mi)
        accA[mi] = __builtin_amdgcn_mfma_f32_32x32x16_bf16(
            af[mi][ks], bgA[ks], accA[mi], 0, 0, 0);
#pragma unroll
    for (int mi = 0; mi < 2; ++mi)
#pragma unroll
      for (int r = 0; r < 16; ++r)
        tmax[mi][r] = fmaxf(tmax[mi][r], accB[mi][r]);

    // Prefetch tile t+2 into bgA (wraps harmlessly at the end).
    {
      const u16* bp2 = bbase + (size_t)((t + 2) & (NT - 1)) * (8 * 64 * 8);
#pragma unroll
      for (int ks = 0; ks < 8; ++ks)
        bgA[ks] = *(const bf16x8*)&bp2[((size_t)ks * 64 + lane) * 8];
      mhA = mhp[((t + 2) & (NT - 1)) * 32];
    }
    // Seed accB, compute tile t+1; fold tile t (accA) meanwhile.
#pragma unroll
    for (int mi = 0; mi < 2; ++mi)
#pragma unroll
      for (int r = 0; r < 16; ++r) accB[mi][r] = mhB;
#pragma unroll
    for (int ks = 0; ks < 8; ++ks)
#pragma unroll
      for (int mi = 0; mi < 2; ++mi)
        accB[mi] = __builtin_amdgcn_mfma_f32_32x32x16_bf16(
            af[mi][ks], bgB[ks], accB[mi], 0, 0, 0);
#pragma unroll
    for (int mi = 0; mi < 2; ++mi)
#pragma unroll
      for (int r = 0; r < 16; ++r)
        tmax[mi][r] = fmaxf(tmax[mi][r], accA[mi][r]);
  }
  // Fold the last odd tile (accB of t=NT-1).
#pragma unroll
  for (int mi = 0; mi < 2; ++mi)
#pragma unroll
    for (int r = 0; r < 16; ++r)
      tmax[mi][r] = fmaxf(tmax[mi][r], accB[mi][r]);

  // Reduce across the 32 lanes (l31) holding a row's B-columns.
#pragma unroll
  for (int mi = 0; mi < 2; ++mi)
#pragma unroll
    for (int r = 0; r < 16; ++r) {
      float tv = tmax[mi][r];
      tv = fmaxf(tv, __shfl_xor(tv, 1, 64));
      tv = fmaxf(tv, __shfl_xor(tv, 2, 64));
      tv = fmaxf(tv, __shfl_xor(tv, 4, 64));
      tv = fmaxf(tv, __shfl_xor(tv, 8, 64));
      tv = fmaxf(tv, __shfl_xor(tv, 16, 64));
      tmax[mi][r] = tv;
    }
  if (l31 == 0) {  // lanes 0 and 32 (l5 = 0/1)
#pragma unroll
    for (int mi = 0; mi < 2; ++mi)
#pragma unroll
      for (int r = 0; r < 16; ++r) {
        // C/D: row = (r&3) + 8*(r>>2) + 4*l5 within the 32-row fragment.
        const int row = abase + w * 64 + mi * 32
                        + (r & 3) + 8 * (r >> 2) + 4 * l5;
        const float d2 = fmaxf(fmaf(-2.0f, tmax[mi][r], f2[row]), 0.0f);
        atomicMin(&mind2[row], __float_as_int(d2));
      }
  }
}

__global__ __launch_bounds__(256) void finalize_kernel(
    const int* __restrict__ mind2, float* __restrict__ out)
{
  const int i = blockIdx.x * 256 + threadIdx.x;
  out[i] = sqrtf(fmaxf(__int_as_float(mind2[i]), 0.0f));
}

extern "C" void kernel_launch(void* const* d_in, const int* in_sizes, int n_in,
                              void* d_out, int out_size, void* d_ws, size_t ws_size,
                              hipStream_t stream) {
  const float* f = (const float*)d_in[0];  // features  [8192,1,1,128] fp32
  const float* m = (const float*)d_in[1];  // patch_mem [1,16384,1,128] fp32

  char* ws = (char*)d_ws;
  u16*  fb    = (u16*)(ws);                                   // 2 MB (fragment order)
  u16*  mb    = (u16*)(ws + (2u << 20));                      // 4 MB (fragment order)
  float* f2   = (float*)(ws + (2u << 20) + (4u << 20));       // 32 KB
  float* mh   = (float*)(ws + (2u << 20) + (4u << 20) + (32u << 10));  // 64 KB
  int*  mind2 = (int*)(ws + (2u << 20) + (4u << 20) + (96u << 10));    // 32 KB

  hipLaunchKernelGGL(prep_kernel, dim3((N_ROWS + M_ROWS) / 4), dim3(256), 0, stream,
                     f, m, fb, mb, f2, mh, mind2);
  hipLaunchKernelGGL(gemm_min_kernel, dim3(MSPLIT, N_ROWS / 256), dim3(256), 0, stream,
                     fb, mb, f2, mh, mind2);
  hipLaunchKernelGGL(finalize_kernel, dim3(N_ROWS / 256), dim3(256), 0, stream,
                     mind2, (float*)d_out);
}

// Round 17
// 52.313 us; speedup vs baseline: 3.0602x; 1.1943x over previous
//
#include <hip/hip_runtime.h>
#include <hip/hip_bf16.h>
#include <stdint.h>

#define N_ROWS 8192
#define M_ROWS 16384
#define CDIM 128
#define MSPLIT 4            // B slices of 4096 rows
#define NT 32               // 128-row B tiles per slice
#define BTR 128             // B rows per tile
#define TILE_U16 (BTR * CDIM)   // 32 KB

typedef unsigned short u16;
typedef __attribute__((ext_vector_type(8))) short bf16x8;
typedef __attribute__((ext_vector_type(16))) float f32x16;

static __device__ __forceinline__ u16 f2bf(float x) {
  union { float f; uint32_t u; } v; v.f = x;
  uint32_t u = v.u;
  uint32_t r = u + 0x7FFFu + ((u >> 16) & 1u);  // RTNE
  return (u16)(r >> 16);
}
static __device__ __forceinline__ float bf2f(u16 b) {
  union { uint32_t u; float f; } v; v.u = ((uint32_t)b) << 16;
  return v.f;
}

#define GLOAD_LDS(gsrc, ldst)                                                  \
  __builtin_amdgcn_global_load_lds(                                            \
      (const __attribute__((address_space(1))) uint32_t*)(gsrc),               \
      (__attribute__((address_space(3))) uint32_t*)(ldst), 16, 0, 0)

// One wave per row. fp32 -> bf16, row sum-of-squares (fp32 accum), and
// FRAGMENT-ORDER store (proven round 12): 16B chunk for (t32=row>>5, ks,
// lane') at ((t32*8+ks)*64+lane')*16B, lane' = l5*32 + (row&31). Every gemm
// fragment access (global or LDS) becomes base+lane*16 -- coalesced /
// bank-conflict-free with zero swizzle logic.
__global__ __launch_bounds__(256) void prep_kernel(
    const float* __restrict__ f, const float* __restrict__ m,
    u16* __restrict__ fb, u16* __restrict__ mb,
    float* __restrict__ f2, float* __restrict__ mh, int* __restrict__ mind2)
{
  const int row = blockIdx.x * 4 + (threadIdx.x >> 6);
  const int lane = threadIdx.x & 63;
  const bool isF = row < N_ROWS;
  const int r = isF ? row : row - N_ROWS;
  const float* src = (isF ? f : m) + (size_t)r * CDIM;
  float2 v = *(const float2*)(src + lane * 2);
  u16 b0 = f2bf(v.x), b1 = f2bf(v.y);
  float x0 = bf2f(b0), x1 = bf2f(b1);
  float s = x0 * x0 + x1 * x1;
#pragma unroll
  for (int mask = 1; mask < 64; mask <<= 1)
    s += __shfl_xor(s, mask, 64);

  const int t = r >> 5, lr = r & 31;
  const int ks = lane >> 3;
  const int l5p = (lane >> 2) & 1;
  const int j = (lane & 3) * 2;
  u16* dst = (isF ? fb : mb)
             + ((size_t)(t * 8 + ks) * 64 + l5p * 32 + lr) * 8 + j;
  dst[0] = b0; dst[1] = b1;
  if (lane == 0) {
    if (isF) { f2[r] = s; mind2[r] = 0x7F7FFFFF; }  // +FLT_MAX bits
    else     { mh[r] = -0.5f * s; }
  }
}

// Round-8 skeleton + round-12 frag-order + 32x32x16 MFMA.
// 512 thr = 8 waves (2 wm x 4 wn); block tile 128A x 128B/tile; wave tile
// 64A x 32B (2 chained mi). A in regs (af[2][8], coalesced frag loads).
// B: LDS triple-buffer 3 x 32 KB, staged as a LINEAR copy of the frag-order
// tile; ds_read_b128 at ((wn*8+ks)*64+lane)*16 -- conflict-free. Schedule
// (R8-proven): per tile ONE s_barrier + counted vmcnt(4); stage tile t+2
// while computing t; the staging queue never drains. Prev-iter vmcnt(4)+
// barrier guarantees tile t landed before this iter's ds_reads.
// acc dual-buffered (accA/accB): fold of tile t-1 runs in tile t's MFMA
// shadow. acc seeded with mh=-m2/2 -> min d2 = f2 - 2*max(acc).
// grid (4 msplit, 64 abase) = 256 blocks = 1 block/CU, ONE pass.
__global__ __launch_bounds__(512, 2) void gemm_min_kernel(
    const u16* __restrict__ fb, const u16* __restrict__ mb,
    const float* __restrict__ f2, const float* __restrict__ mh,
    int* __restrict__ mind2)
{
  __shared__ __align__(16) u16 bts[3 * TILE_U16];  // 96 KB
  __shared__ __align__(16) float mhl[4096];        // 16 KB
  const int tid = threadIdx.x;
  const int lane = tid & 63;
  const int w = tid >> 6;       // 0..7
  const int wm = w >> 2;        // 0..1 : 64-row A group
  const int wn = w & 3;         // 0..3 : 32-row B group
  const int l31 = lane & 31;
  const int l5 = lane >> 5;
  const int abase = blockIdx.y * 128;
  const size_t mslice = (size_t)blockIdx.x * 4096;

  // A fragments (frag-order, coalesced), issued first so the prologue
  // vmcnt(4) also covers them.
  bf16x8 af[2][8];  // [mi][ks]
#pragma unroll
  for (int mi = 0; mi < 2; ++mi) {
    const int ta = (abase >> 5) + wm * 2 + mi;
#pragma unroll
    for (int ks = 0; ks < 8; ++ks)
      af[mi][ks] = *(const bf16x8*)&fb[((size_t)(ta * 8 + ks) * 64 + lane) * 8];
  }

  // Prologue staging: mh slice (16 KB) + tiles 0,1.
  const float* mhsrc = mh + mslice;
#pragma unroll
  for (int c = 0; c < 2; ++c) {
    const int c16 = c * 512 + tid;
    GLOAD_LDS(mhsrc + c16 * 4, mhl + c16 * 4);
  }
  const u16* mbase_ptr = mb + mslice * CDIM;  // frag-order, linear per tile
#pragma unroll
  for (int tt = 0; tt < 2; ++tt)
#pragma unroll
    for (int c = 0; c < 4; ++c) {
      const int t16 = c * 512 + tid;
      GLOAD_LDS(mbase_ptr + (size_t)tt * TILE_U16 + t16 * 8,
                bts + tt * TILE_U16 + t16 * 8);
    }
  asm volatile("s_waitcnt vmcnt(4)" ::: "memory");  // af+mh+tile0 retired
  __builtin_amdgcn_s_barrier();

  float tmax[2][16];
#pragma unroll
  for (int mi = 0; mi < 2; ++mi)
#pragma unroll
    for (int r = 0; r < 16; ++r) tmax[mi][r] = -3.0e38f;

  f32x16 accA[2], accB[2];
#pragma unroll
  for (int mi = 0; mi < 2; ++mi)
#pragma unroll
    for (int r = 0; r < 16; ++r) accB[mi][r] = -3.0e38f;  // first fold no-op

  const int wnoff = wn * (8 * 64 * 8);  // frag-tile offset in u16
  int c0 = 0;                           // t % 3

  for (int t = 0; t < NT; t += 2) {
    int c1 = c0 + 1; if (c1 >= 3) c1 -= 3;
    int c2 = c0 + 2; if (c2 >= 3) c2 -= 3;

    // ---- tile t (buf c0) ----
    {
      const u16* bt = bts + c0 * TILE_U16 + wnoff;
      bf16x8 bg[8];
#pragma unroll
      for (int ks = 0; ks < 8; ++ks)
        bg[ks] = *(const bf16x8*)&bt[((size_t)ks * 64 + lane) * 8];
      const float mhA = mhl[t * BTR + wn * 32 + l31];
      // stage tile t+2 -> buf c2
      {
        const u16* srcT = mbase_ptr + (size_t)((t + 2) & (NT - 1)) * TILE_U16;
        u16* dstT = bts + c2 * TILE_U16;
#pragma unroll
        for (int c = 0; c < 4; ++c) {
          const int t16 = c * 512 + tid;
          GLOAD_LDS(srcT + t16 * 8, dstT + t16 * 8);
        }
      }
      asm volatile("s_waitcnt vmcnt(4)" ::: "memory");  // tile t+1 landed
      __builtin_amdgcn_s_barrier();

#pragma unroll
      for (int mi = 0; mi < 2; ++mi)
#pragma unroll
        for (int r = 0; r < 16; ++r) accA[mi][r] = mhA;
      __builtin_amdgcn_s_setprio(1);
#pragma unroll
      for (int ks = 0; ks < 8; ++ks)
#pragma unroll
        for (int mi = 0; mi < 2; ++mi)
          accA[mi] = __builtin_amdgcn_mfma_f32_32x32x16_bf16(
              af[mi][ks], bg[ks], accA[mi], 0, 0, 0);
      __builtin_amdgcn_s_setprio(0);
      // fold tile t-1 (accB) in the MFMA shadow
#pragma unroll
      for (int mi = 0; mi < 2; ++mi)
#pragma unroll
        for (int r = 0; r < 16; ++r)
          tmax[mi][r] = fmaxf(tmax[mi][r], accB[mi][r]);
    }

    // ---- tile t+1 (buf c1) ----
    {
      const u16* bt = bts + c1 * TILE_U16 + wnoff;
      bf16x8 bg[8];
#pragma unroll
      for (int ks = 0; ks < 8; ++ks)
        bg[ks] = *(const bf16x8*)&bt[((size_t)ks * 64 + lane) * 8];
      const float mhB = mhl[(t + 1) * BTR + wn * 32 + l31];
      // stage tile t+3 -> buf c0 (its tile-t readers finished pre-barrier)
      {
        const u16* srcT = mbase_ptr + (size_t)((t + 3) & (NT - 1)) * TILE_U16;
        u16* dstT = bts + c0 * TILE_U16;
#pragma unroll
        for (int c = 0; c < 4; ++c) {
          const int t16 = c * 512 + tid;
          GLOAD_LDS(srcT + t16 * 8, dstT + t16 * 8);
        }
      }
      asm volatile("s_waitcnt vmcnt(4)" ::: "memory");  // tile t+2 landed
      __builtin_amdgcn_s_barrier();

#pragma unroll
      for (int mi = 0; mi < 2; ++mi)
#pragma unroll
        for (int r = 0; r < 16; ++r) accB[mi][r] = mhB;
      __builtin_amdgcn_s_setprio(1);
#pragma unroll
      for (int ks = 0; ks < 8; ++ks)
#pragma unroll
        for (int mi = 0; mi < 2; ++mi)
          accB[mi] = __builtin_amdgcn_mfma_f32_32x32x16_bf16(
              af[mi][ks], bg[ks], accB[mi], 0, 0, 0);
      __builtin_amdgcn_s_setprio(0);
      // fold tile t (accA)
#pragma unroll
      for (int mi = 0; mi < 2; ++mi)
#pragma unroll
        for (int r = 0; r < 16; ++r)
          tmax[mi][r] = fmaxf(tmax[mi][r], accA[mi][r]);
    }
    c0 = c2;
  }
  // fold the last tile (accB of t=NT-1)
#pragma unroll
  for (int mi = 0; mi < 2; ++mi)
#pragma unroll
    for (int r = 0; r < 16; ++r)
      tmax[mi][r] = fmaxf(tmax[mi][r], accB[mi][r]);

  // Reduce across the 32 lanes (l31) holding a row's B-columns.
#pragma unroll
  for (int mi = 0; mi < 2; ++mi)
#pragma unroll
    for (int r = 0; r < 16; ++r) {
      float tv = tmax[mi][r];
      tv = fmaxf(tv, __shfl_xor(tv, 1, 64));
      tv = fmaxf(tv, __shfl_xor(tv, 2, 64));
      tv = fmaxf(tv, __shfl_xor(tv, 4, 64));
      tv = fmaxf(tv, __shfl_xor(tv, 8, 64));
      tv = fmaxf(tv, __shfl_xor(tv, 16, 64));
      tmax[mi][r] = tv;
    }
  if (l31 == 0) {  // lanes 0 and 32 (l5 = 0/1)
#pragma unroll
    for (int mi = 0; mi < 2; ++mi)
#pragma unroll
      for (int r = 0; r < 16; ++r) {
        // C/D: row = (r&3) + 8*(r>>2) + 4*l5 within the 32-row fragment.
        const int row = abase + wm * 64 + mi * 32
                        + (r & 3) + 8 * (r >> 2) + 4 * l5;
        const float d2 = fmaxf(fmaf(-2.0f, tmax[mi][r], f2[row]), 0.0f);
        atomicMin(&mind2[row], __float_as_int(d2));
      }
  }
}

__global__ __launch_bounds__(256) void finalize_kernel(
    const int* __restrict__ mind2, float* __restrict__ out)
{
  const int i = blockIdx.x * 256 + threadIdx.x;
  out[i] = sqrtf(fmaxf(__int_as_float(mind2[i]), 0.0f));
}

extern "C" void kernel_launch(void* const* d_in, const int* in_sizes, int n_in,
                              void* d_out, int out_size, void* d_ws, size_t ws_size,
                              hipStream_t stream) {
  const float* f = (const float*)d_in[0];  // features  [8192,1,1,128] fp32
  const float* m = (const float*)d_in[1];  // patch_mem [1,16384,1,128] fp32

  char* ws = (char*)d_ws;
  u16*  fb    = (u16*)(ws);                                   // 2 MB (frag order)
  u16*  mb    = (u16*)(ws + (2u << 20));                      // 4 MB (frag order)
  float* f2   = (float*)(ws + (2u << 20) + (4u << 20));       // 32 KB
  float* mh   = (float*)(ws + (2u << 20) + (4u << 20) + (32u << 10));  // 64 KB
  int*  mind2 = (int*)(ws + (2u << 20) + (4u << 20) + (96u << 10));    // 32 KB

  hipLaunchKernelGGL(prep_kernel, dim3((N_ROWS + M_ROWS) / 4), dim3(256), 0, stream,
                     f, m, fb, mb, f2, mh, mind2);
  hipLaunchKernelGGL(gemm_min_kernel, dim3(MSPLIT, N_ROWS / 128), dim3(512), 0, stream,
                     fb, mb, f2, mh, mind2);
  hipLaunchKernelGGL(finalize_kernel, dim3(N_ROWS / 256), dim3(256), 0, stream,
                     mind2, (float*)d_out);
}